// Round 1
// baseline (750.273 us; speedup 1.0000x reference)
//
#include <hip/hip_runtime.h>
#include <hip/hip_bf16.h>
#include <stdint.h>

#define DEV static __device__ __forceinline__

typedef __attribute__((ext_vector_type(8))) short bf16x8;
typedef __attribute__((ext_vector_type(4))) float f32x4;

static constexpr int T = 4096;
static constexpr int BATCH = 8;
static constexpr int DM = 1024;            // d_model = nhead*d_head
static constexpr int M1 = BATCH * T;       // 32768 rows into GEMM1
static constexpr int M2 = BATCH * (T + 1); // 32776 rows into GEMM2
static constexpr int M2P = 257 * 128;      // 32896 padded rows for S
static constexpr int NCH = 64;             // time chunks for scan
static constexpr int CL = T / NCH;         // 64 steps per chunk

DEV unsigned short f2bf(float f) {
  union { float f; unsigned u; } v; v.f = f;
  unsigned u = v.u;
  return (unsigned short)((u + 0x7fffu + ((u >> 16) & 1u)) >> 16);
}
DEV float bf2f(unsigned short s) {
  union { unsigned u; float f; } v; v.u = ((unsigned)s) << 16;
  return v.f;
}

// ---------------- fp32 -> bf16 convert of inputs ----------------
__global__ void k_cvt_x(const float4* __restrict__ x, ushort4* __restrict__ o) {
  int i = blockIdx.x * 256 + threadIdx.x;   // 8388608 float4s
  float4 v = x[i];
  ushort4 r;
  r.x = f2bf(v.x); r.y = f2bf(v.y); r.z = f2bf(v.z); r.w = f2bf(v.w);
  o[i] = r;
}

// ------------- transpose + convert weights: Wt[n][k] = W[k][n] -------------
__global__ void k_transpose(const float* __restrict__ w0, const float* __restrict__ w1,
                            unsigned short* __restrict__ t0, unsigned short* __restrict__ t1) {
  __shared__ float tile[32][33];
  const float* src = blockIdx.z ? w1 : w0;
  unsigned short* dst = blockIdx.z ? t1 : t0;
  int bx = blockIdx.x * 32;  // n (col of W)
  int by = blockIdx.y * 32;  // k (row of W)
  int tx = threadIdx.x & 31, ty = threadIdx.x >> 5;  // 256 threads
#pragma unroll
  for (int r = 0; r < 32; r += 8)
    tile[ty + r][tx] = src[(by + ty + r) * DM + bx + tx];
  __syncthreads();
#pragma unroll
  for (int r = 0; r < 32; r += 8)
    dst[(bx + ty + r) * DM + by + tx] = f2bf(tile[tx][ty + r]);
}

// ---------------- bf16 MFMA GEMM: C = A @ Wt^T + bias ----------------
// A16: [M][1024] bf16 row-major (k contiguous). Bt16: [1024 n][1024 k] bf16.
// 128x128 tile, 4 waves, each 64x64 = 4x4 frags of 16x16x32.
// MODE 0: bf16 out (proj), all rows valid. MODE 1: fp32 out, rows < Mvalid.
template <int MODE>
__global__ __launch_bounds__(256, 2) void k_gemm(const unsigned short* __restrict__ A16,
                                                 const unsigned short* __restrict__ Bt16,
                                                 const float* __restrict__ bias,
                                                 unsigned short* __restrict__ outb,
                                                 float* __restrict__ outf, int Mvalid) {
  __shared__ unsigned short sA[128 * 32];  // [row][32 k] bf16, granule-swizzled
  __shared__ unsigned short sB[128 * 32];

  const int tid = threadIdx.x;
  const int w = tid >> 6, l = tid & 63;
  const int bm = blockIdx.x >> 3, bn = blockIdx.x & 7;
  const int blockM = bm * 128;
  const int blockN = bn * 128;
  const int wr = (w >> 1) * 64, wc = (w & 1) * 64;

  // staging: thread covers (row = c*64 + tid/4, logical granule g = tid&3)
  const int srow0 = tid >> 2;
  const int sg = tid & 3;

  f32x4 acc[4][4];
#pragma unroll
  for (int m = 0; m < 4; m++)
#pragma unroll
    for (int n = 0; n < 4; n++) acc[m][n] = (f32x4){0.f, 0.f, 0.f, 0.f};

  uint4 ra[2], rb[2];

  auto load_regs = [&](int kt) {
    const int k0 = kt * 32;
#pragma unroll
    for (int c = 0; c < 2; c++) {
      int r = c * 64 + srow0;
      ra[c] = *(const uint4*)(A16 + (blockM + r) * DM + k0 + sg * 8);
      rb[c] = *(const uint4*)(Bt16 + (blockN + r) * DM + k0 + sg * 8);
    }
  };
  auto write_lds = [&]() {
#pragma unroll
    for (int c = 0; c < 2; c++) {
      int r = c * 64 + srow0;
      int gp = sg ^ ((r >> 1) & 3);  // XOR swizzle spreads rows across banks
      *(uint4*)(sA + r * 32 + gp * 8) = ra[c];
      *(uint4*)(sB + r * 32 + gp * 8) = rb[c];
    }
  };

  load_regs(0);
  write_lds();
  __syncthreads();

  const int kg = l >> 4;   // k-granule 0..3 (8 bf16 each)
  const int rr = l & 15;   // row-within-frag

  for (int kt = 0; kt < 32; ++kt) {
    if (kt + 1 < 32) load_regs(kt + 1);
    bf16x8 af[4], bfr[4];
#pragma unroll
    for (int m = 0; m < 4; m++) {
      int r = wr + m * 16 + rr;
      int gp = kg ^ ((r >> 1) & 3);
      af[m] = *(const bf16x8*)(sA + r * 32 + gp * 8);
    }
#pragma unroll
    for (int n = 0; n < 4; n++) {
      int r = wc + n * 16 + rr;
      int gp = kg ^ ((r >> 1) & 3);
      bfr[n] = *(const bf16x8*)(sB + r * 32 + gp * 8);
    }
#pragma unroll
    for (int m = 0; m < 4; m++)
#pragma unroll
      for (int n = 0; n < 4; n++)
        acc[m][n] = __builtin_amdgcn_mfma_f32_16x16x32_bf16(af[m], bfr[n], acc[m][n], 0, 0, 0);
    __syncthreads();
    if (kt + 1 < 32) {
      write_lds();
      __syncthreads();
    }
  }

  // epilogue: C/D mapping col=lane&15, row=(lane>>4)*4+j  [m89-verified]
#pragma unroll
  for (int m = 0; m < 4; m++) {
    int row = blockM + wr + m * 16 + (l >> 4) * 4;
#pragma unroll
    for (int n = 0; n < 4; n++) {
      int col = blockN + wc + n * 16 + (l & 15);
      float bv = bias[col];
#pragma unroll
      for (int j = 0; j < 4; j++) {
        float v = acc[m][n][j] + bv;
        if (MODE == 0) {
          outb[(row + j) * DM + col] = f2bf(v);
        } else {
          if (row + j < Mvalid) outf[(size_t)(row + j) * DM + col] = v;
        }
      }
    }
  }
}

// ---------------- scan phase A: per-chunk local (zero-init) end state ----------------
__global__ void k_scan_partial(const unsigned short* __restrict__ proj,
                               const float* __restrict__ logit,
                               const float* __restrict__ z0,
                               float* __restrict__ chunkend) {
  int b = blockIdx.x >> 6, c = blockIdx.x & 63;
  int ch = threadIdx.x;  // 1024 channels = h*64+d
  float a = 1.f / (1.f + expf(-logit[ch >> 6]));
  int t0 = c * CL;
  const unsigned short* p = proj + (size_t)(b * T + t0) * DM + ch;
  float pprev = (t0 == 0) ? z0[ch] : bf2f(p[-DM]);
  float s = 0.f;
  for (int j = 0; j < CL; j++) {
    float pv = bf2f(p[(size_t)j * DM]);
    s = a * s + (1.f - a) * (pv - pprev);
    pprev = pv;
  }
  chunkend[(b * NCH + c) * DM + ch] = s;
}

// ---------------- scan phase B: serial cross-chunk combine ----------------
__global__ void k_scan_combine(const float* __restrict__ chunkend,
                               const float* __restrict__ logit,
                               const float* __restrict__ v0,
                               float* __restrict__ enter) {
  int b = blockIdx.x;
  int ch = threadIdx.x;
  float a = 1.f / (1.f + expf(-logit[ch >> 6]));
  float a2 = a * a, a4 = a2 * a2, a8 = a4 * a4, a16 = a8 * a8, a32 = a16 * a16;
  float aL = a32 * a32;  // a^64 exact-ish
  float e = v0[ch];      // s_{-1}
  enter[(b * NCH + 0) * DM + ch] = e;
  for (int c = 1; c < NCH; c++) {
    e = aL * e + chunkend[(b * NCH + c - 1) * DM + ch];
    enter[(b * NCH + c) * DM + ch] = e;
  }
}

// ---------------- scan phase C: final scan with entry states, write S (bf16) ----------------
__global__ void k_scan_final(const unsigned short* __restrict__ proj,
                             const float* __restrict__ logit,
                             const float* __restrict__ z0,
                             const float* __restrict__ v0,
                             const float* __restrict__ enter,
                             unsigned short* __restrict__ S) {
  int b = blockIdx.x >> 6, c = blockIdx.x & 63;
  int ch = threadIdx.x;
  float a = 1.f / (1.f + expf(-logit[ch >> 6]));
  int t0 = c * CL;
  const unsigned short* p = proj + (size_t)(b * T + t0) * DM + ch;
  unsigned short* so = S + (size_t)(b * (T + 1) + t0 + 1) * DM + ch;
  float pprev = (t0 == 0) ? z0[ch] : bf2f(p[-DM]);
  float s = enter[(b * NCH + c) * DM + ch];
  if (c == 0) S[(size_t)b * (T + 1) * DM + ch] = f2bf(v0[ch]);  // row 0 = v0
  for (int j = 0; j < CL; j++) {
    float pv = bf2f(p[(size_t)j * DM]);
    s = a * s + (1.f - a) * (pv - pprev);
    pprev = pv;
    so[(size_t)j * DM] = f2bf(s);
  }
}

// zero the padded S rows [M2, M2P) so GEMM2 staging reads are benign
__global__ void k_pad(unsigned short* __restrict__ S) {
  int i = blockIdx.x * 256 + threadIdx.x;  // 120*1024 elements
  S[(size_t)M2 * DM + i] = 0;
}

extern "C" void kernel_launch(void* const* d_in, const int* in_sizes, int n_in,
                              void* d_out, int out_size, void* d_ws, size_t ws_size,
                              hipStream_t stream) {
  const float* inputs = (const float*)d_in[0];
  const float* z0     = (const float*)d_in[1];
  const float* W_in   = (const float*)d_in[2];
  const float* b_in   = (const float*)d_in[3];
  const float* W_out  = (const float*)d_in[4];
  const float* b_out  = (const float*)d_in[5];
  const float* slogit = (const float*)d_in[6];
  const float* v0     = (const float*)d_in[7];
  float* out = (float*)d_out;

  char* ws = (char*)d_ws;
  unsigned short* X16   = (unsigned short*)(ws);                    // 67,108,864 B
  unsigned short* P16   = (unsigned short*)(ws + 67108864);         // 67,108,864 B
  unsigned short* S16   = (unsigned short*)(ws + 134217728);        // 67,371,008 B (padded)
  unsigned short* WTin  = (unsigned short*)(ws + 201588736);        // 2,097,152 B
  unsigned short* WTout = (unsigned short*)(ws + 203685888);        // 2,097,152 B
  float* chunkend       = (float*)(ws + 205783040);                 // 2,097,152 B
  float* enter          = (float*)(ws + 207880192);                 // 2,097,152 B

  // 1. convert inputs to bf16
  k_cvt_x<<<32768, 256, 0, stream>>>((const float4*)inputs, (ushort4*)X16);
  // 2. transpose+convert both weights
  k_transpose<<<dim3(32, 32, 2), 256, 0, stream>>>(W_in, W_out, WTin, WTout);
  // 3. GEMM1: proj = inputs @ W_in + b_in   (bf16 out)
  k_gemm<0><<<dim3((M1 / 128) * 8), 256, 0, stream>>>(X16, WTin, b_in, P16, nullptr, M1);
  // 4. scan: temporal diff + exponential smoothing
  k_scan_partial<<<dim3(BATCH * NCH), 1024, 0, stream>>>(P16, slogit, z0, chunkend);
  k_scan_combine<<<dim3(BATCH), 1024, 0, stream>>>(chunkend, slogit, v0, enter);
  k_scan_final<<<dim3(BATCH * NCH), 1024, 0, stream>>>(P16, slogit, z0, v0, enter, S16);
  k_pad<<<dim3(480), 256, 0, stream>>>(S16);
  // 5. GEMM2: out = S @ W_out + b_out  (fp32 out, 32776 valid rows of 32896)
  k_gemm<1><<<dim3((M2P / 128) * 8), 256, 0, stream>>>(S16, WTout, b_out, nullptr, out, M2);
}

// Round 2
// 315.261 us; speedup vs baseline: 2.3798x; 2.3798x over previous
//
#include <hip/hip_runtime.h>
#include <hip/hip_bf16.h>
#include <stdint.h>

#define DEV static __device__ __forceinline__

typedef __attribute__((ext_vector_type(8))) short bf16x8;
typedef __attribute__((ext_vector_type(4))) float f32x4;
typedef unsigned int u32;

static constexpr int T = 4096;
static constexpr int BATCH = 8;
static constexpr int DM = 1024;            // d_model = nhead*d_head
static constexpr int M1 = BATCH * T;       // 32768 rows into GEMM1
static constexpr int M2 = BATCH * (T + 1); // 32776 rows into GEMM2
static constexpr int M2P = 257 * 128;      // 32896 padded rows for S
static constexpr int NCH = 64;             // time chunks for scan
static constexpr int CL = T / NCH;         // 64 steps per chunk

DEV unsigned short f2bf(float f) {
  union { float f; unsigned u; } v; v.f = f;
  unsigned u = v.u;
  return (unsigned short)((u + 0x7fffu + ((u >> 16) & 1u)) >> 16);
}
DEV float bf2f(unsigned short s) {
  union { unsigned u; float f; } v; v.u = ((unsigned)s) << 16;
  return v.f;
}

// async global->LDS, 16B per lane. lds must be wave-uniform base; g is per-lane.
DEV void gl_lds16(const unsigned short* g, unsigned short* lds) {
  __builtin_amdgcn_global_load_lds(
      (const __attribute__((address_space(1))) u32*)g,
      (__attribute__((address_space(3))) u32*)lds,
      16, 0, 0);
}

// ---------------- fp32 -> bf16 convert of inputs ----------------
__global__ void k_cvt_x(const float4* __restrict__ x, ushort4* __restrict__ o) {
  int i = blockIdx.x * 256 + threadIdx.x;   // 8388608 float4s
  float4 v = x[i];
  ushort4 r;
  r.x = f2bf(v.x); r.y = f2bf(v.y); r.z = f2bf(v.z); r.w = f2bf(v.w);
  o[i] = r;
}

// ------------- transpose + convert weights: Wt[n][k] = W[k][n] -------------
__global__ void k_transpose(const float* __restrict__ w0, const float* __restrict__ w1,
                            unsigned short* __restrict__ t0, unsigned short* __restrict__ t1) {
  __shared__ float tile[32][33];
  const float* src = blockIdx.z ? w1 : w0;
  unsigned short* dst = blockIdx.z ? t1 : t0;
  int bx = blockIdx.x * 32;  // n (col of W)
  int by = blockIdx.y * 32;  // k (row of W)
  int tx = threadIdx.x & 31, ty = threadIdx.x >> 5;  // 256 threads
#pragma unroll
  for (int r = 0; r < 32; r += 8)
    tile[ty + r][tx] = src[(by + ty + r) * DM + bx + tx];
  __syncthreads();
#pragma unroll
  for (int r = 0; r < 32; r += 8)
    dst[(bx + ty + r) * DM + by + tx] = f2bf(tile[tx][ty + r]);
}

// ---------------- bf16 MFMA GEMM: C = A @ Wt^T + bias ----------------
// m97 structure: 128x128 tile, BK=32, single-buffer LDS [128][32] linear,
// global_load_lds width-16 staging, 2 barriers per K-step, 4 waves 4x4 frags.
// MODE 0: bf16 out (proj). MODE 1: fp32 out, rows < Mvalid.
template <int MODE>
__global__ __launch_bounds__(256) void k_gemm(const unsigned short* __restrict__ A16,
                                              const unsigned short* __restrict__ Bt16,
                                              const float* __restrict__ bias,
                                              unsigned short* __restrict__ outb,
                                              float* __restrict__ outf, int Mvalid) {
  __shared__ unsigned short sA[128 * 32];  // [row][32 k] bf16, linear
  __shared__ unsigned short sB[128 * 32];

  const int tid = threadIdx.x;
  const int w = tid >> 6, l = tid & 63;

  // bijective XCD swizzle (nwg % 8 == 0 for both grids)
  const int nwg = gridDim.x;
  const int cpx = nwg >> 3;
  const int orig = blockIdx.x;
  const int wg = (orig & 7) * cpx + (orig >> 3);
  const int bm = wg >> 3, bn = wg & 7;
  const int blockM = bm * 128;
  const int blockN = bn * 128;
  const int wr = (w >> 1) * 64, wc = (w & 1) * 64;

  f32x4 acc[4][4];
#pragma unroll
  for (int m = 0; m < 4; m++)
#pragma unroll
    for (int n = 0; n < 4; n++) acc[m][n] = (f32x4){0.f, 0.f, 0.f, 0.f};

  // staging geometry: granule gi = c*256 + tid; row = gi>>2; slot = gi&3 (16B each)
  const int srow0 = tid >> 2;      // row covered at c=0 (c=1 adds 64)
  const int sslot = tid & 3;

  auto stage = [&](int kt) {
    const int k0 = kt * 32;
#pragma unroll
    for (int c = 0; c < 2; c++) {
      const int row = c * 64 + srow0;
      const unsigned short* gA = A16 + (size_t)(blockM + row) * DM + k0 + sslot * 8;
      const unsigned short* gB = Bt16 + (size_t)(blockN + row) * DM + k0 + sslot * 8;
      unsigned short* lA = sA + c * 2048 + w * 512;  // wave-uniform base (bytes: c*4096 + w*1024)
      unsigned short* lB = sB + c * 2048 + w * 512;
      gl_lds16(gA, lA);
      gl_lds16(gB, lB);
    }
  };

  const int kg = l >> 4;   // k-granule 0..3 (8 bf16 each)
  const int rr = l & 15;   // row-within-frag

  stage(0);
  __syncthreads();

  for (int kt = 0; kt < 32; ++kt) {
    bf16x8 af[4], bfr[4];
#pragma unroll
    for (int m = 0; m < 4; m++)
      af[m] = *(const bf16x8*)(sA + (wr + m * 16 + rr) * 32 + kg * 8);
#pragma unroll
    for (int n = 0; n < 4; n++)
      bfr[n] = *(const bf16x8*)(sB + (wc + n * 16 + rr) * 32 + kg * 8);
#pragma unroll
    for (int m = 0; m < 4; m++)
#pragma unroll
      for (int n = 0; n < 4; n++)
        acc[m][n] = __builtin_amdgcn_mfma_f32_16x16x32_bf16(af[m], bfr[n], acc[m][n], 0, 0, 0);
    __syncthreads();              // all reads of this tile done
    if (kt + 1 < 32) {
      stage(kt + 1);
      __syncthreads();            // staging complete (vmcnt drained by compiler)
    }
  }

  // epilogue: C/D mapping col=lane&15, row=(lane>>4)*4+j  [m89-verified]
#pragma unroll
  for (int m = 0; m < 4; m++) {
    int row = blockM + wr + m * 16 + (l >> 4) * 4;
#pragma unroll
    for (int n = 0; n < 4; n++) {
      int col = blockN + wc + n * 16 + (l & 15);
      float bv = bias[col];
#pragma unroll
      for (int j = 0; j < 4; j++) {
        float v = acc[m][n][j] + bv;
        if (MODE == 0) {
          outb[(size_t)(row + j) * DM + col] = f2bf(v);
        } else {
          if (row + j < Mvalid) outf[(size_t)(row + j) * DM + col] = v;
        }
      }
    }
  }
}

// ---------------- scan phase A: per-chunk local (zero-init) end state ----------------
__global__ void k_scan_partial(const unsigned short* __restrict__ proj,
                               const float* __restrict__ logit,
                               const float* __restrict__ z0,
                               float* __restrict__ chunkend) {
  int b = blockIdx.x >> 6, c = blockIdx.x & 63;
  int ch = threadIdx.x;  // 1024 channels = h*64+d
  float a = 1.f / (1.f + expf(-logit[ch >> 6]));
  int t0 = c * CL;
  const unsigned short* p = proj + (size_t)(b * T + t0) * DM + ch;
  float pprev = (t0 == 0) ? z0[ch] : bf2f(p[-DM]);
  float s = 0.f;
  for (int j = 0; j < CL; j++) {
    float pv = bf2f(p[(size_t)j * DM]);
    s = a * s + (1.f - a) * (pv - pprev);
    pprev = pv;
  }
  chunkend[(b * NCH + c) * DM + ch] = s;
}

// ---------------- scan phase B: serial cross-chunk combine ----------------
__global__ void k_scan_combine(const float* __restrict__ chunkend,
                               const float* __restrict__ logit,
                               const float* __restrict__ v0,
                               float* __restrict__ enter) {
  int b = blockIdx.x;
  int ch = threadIdx.x;
  float a = 1.f / (1.f + expf(-logit[ch >> 6]));
  float a2 = a * a, a4 = a2 * a2, a8 = a4 * a4, a16 = a8 * a8, a32 = a16 * a16;
  float aL = a32 * a32;  // a^64
  float e = v0[ch];      // s_{-1}
  enter[(b * NCH + 0) * DM + ch] = e;
  for (int c = 1; c < NCH; c++) {
    e = aL * e + chunkend[(b * NCH + c - 1) * DM + ch];
    enter[(b * NCH + c) * DM + ch] = e;
  }
}

// ---------------- scan phase C: final scan with entry states, write S (bf16) ----------------
__global__ void k_scan_final(const unsigned short* __restrict__ proj,
                             const float* __restrict__ logit,
                             const float* __restrict__ z0,
                             const float* __restrict__ v0,
                             const float* __restrict__ enter,
                             unsigned short* __restrict__ S) {
  int b = blockIdx.x >> 6, c = blockIdx.x & 63;
  int ch = threadIdx.x;
  float a = 1.f / (1.f + expf(-logit[ch >> 6]));
  int t0 = c * CL;
  const unsigned short* p = proj + (size_t)(b * T + t0) * DM + ch;
  unsigned short* so = S + (size_t)(b * (T + 1) + t0 + 1) * DM + ch;
  float pprev = (t0 == 0) ? z0[ch] : bf2f(p[-DM]);
  float s = enter[(b * NCH + c) * DM + ch];
  if (c == 0) S[(size_t)b * (T + 1) * DM + ch] = f2bf(v0[ch]);  // row 0 = v0
  for (int j = 0; j < CL; j++) {
    float pv = bf2f(p[(size_t)j * DM]);
    s = a * s + (1.f - a) * (pv - pprev);
    pprev = pv;
    so[(size_t)j * DM] = f2bf(s);
  }
}

// zero the padded S rows [M2, M2P) so GEMM2 staging reads are benign
__global__ void k_pad(unsigned short* __restrict__ S) {
  int i = blockIdx.x * 256 + threadIdx.x;  // 120*1024 elements
  S[(size_t)M2 * DM + i] = 0;
}

extern "C" void kernel_launch(void* const* d_in, const int* in_sizes, int n_in,
                              void* d_out, int out_size, void* d_ws, size_t ws_size,
                              hipStream_t stream) {
  const float* inputs = (const float*)d_in[0];
  const float* z0     = (const float*)d_in[1];
  const float* W_in   = (const float*)d_in[2];
  const float* b_in   = (const float*)d_in[3];
  const float* W_out  = (const float*)d_in[4];
  const float* b_out  = (const float*)d_in[5];
  const float* slogit = (const float*)d_in[6];
  const float* v0     = (const float*)d_in[7];
  float* out = (float*)d_out;

  char* ws = (char*)d_ws;
  unsigned short* X16   = (unsigned short*)(ws);                    // 67,108,864 B
  unsigned short* P16   = (unsigned short*)(ws + 67108864);         // 67,108,864 B
  unsigned short* S16   = (unsigned short*)(ws + 134217728);        // 67,371,008 B (padded)
  unsigned short* WTin  = (unsigned short*)(ws + 201588736);        // 2,097,152 B
  unsigned short* WTout = (unsigned short*)(ws + 203685888);        // 2,097,152 B
  float* chunkend       = (float*)(ws + 205783040);                 // 2,097,152 B
  float* enter          = (float*)(ws + 207880192);                 // 2,097,152 B

  // 1. convert inputs to bf16
  k_cvt_x<<<32768, 256, 0, stream>>>((const float4*)inputs, (ushort4*)X16);
  // 2. transpose+convert both weights
  k_transpose<<<dim3(32, 32, 2), 256, 0, stream>>>(W_in, W_out, WTin, WTout);
  // 3. GEMM1: proj = inputs @ W_in + b_in   (bf16 out)
  k_gemm<0><<<dim3((M1 / 128) * 8), 256, 0, stream>>>(X16, WTin, b_in, P16, nullptr, M1);
  // 4. scan: temporal diff + exponential smoothing
  k_scan_partial<<<dim3(BATCH * NCH), 1024, 0, stream>>>(P16, slogit, z0, chunkend);
  k_scan_combine<<<dim3(BATCH), 1024, 0, stream>>>(chunkend, slogit, v0, enter);
  k_scan_final<<<dim3(BATCH * NCH), 1024, 0, stream>>>(P16, slogit, z0, v0, enter, S16);
  k_pad<<<dim3(480), 256, 0, stream>>>(S16);
  // 5. GEMM2: out = S @ W_out + b_out  (fp32 out, 32776 valid rows of 32896)
  k_gemm<1><<<dim3((M2P / 128) * 8), 256, 0, stream>>>(S16, WTout, b_out, nullptr, out, M2);
}

// Round 3
// 301.461 us; speedup vs baseline: 2.4888x; 1.0458x over previous
//
#include <hip/hip_runtime.h>
#include <hip/hip_bf16.h>
#include <stdint.h>

#define DEV static __device__ __forceinline__

typedef __attribute__((ext_vector_type(8))) short bf16x8;
typedef __attribute__((ext_vector_type(4))) float f32x4;
typedef unsigned int u32;

static constexpr int T = 4096;
static constexpr int BATCH = 8;
static constexpr int DM = 1024;            // d_model = nhead*d_head
static constexpr int M1 = BATCH * T;       // 32768 rows into GEMM1
static constexpr int M2 = BATCH * (T + 1); // 32776 rows into GEMM2
static constexpr int M2P = 129 * 256;      // 33024 padded rows for S (256-tile)
static constexpr int NCH = 64;             // time chunks for scan
static constexpr int CL = T / NCH;         // 64 steps per chunk
static constexpr int NT = 32;              // K tiles (BK=32, K=1024)

DEV unsigned short f2bf(float f) {
  union { float f; unsigned u; } v; v.f = f;
  unsigned u = v.u;
  return (unsigned short)((u + 0x7fffu + ((u >> 16) & 1u)) >> 16);
}
DEV float bf2f(unsigned short s) {
  union { unsigned u; float f; } v; v.u = ((unsigned)s) << 16;
  return v.f;
}

// async global->LDS, 16B per lane. lds must be wave-uniform base; g is per-lane.
DEV void gl_lds16(const unsigned short* g, unsigned short* lds) {
  __builtin_amdgcn_global_load_lds(
      (const __attribute__((address_space(1))) u32*)g,
      (__attribute__((address_space(3))) u32*)lds,
      16, 0, 0);
}

// ---------------- fp32 -> bf16 convert of inputs ----------------
__global__ void k_cvt_x(const float4* __restrict__ x, ushort4* __restrict__ o) {
  int i = blockIdx.x * 256 + threadIdx.x;   // 8388608 float4s
  float4 v = x[i];
  ushort4 r;
  r.x = f2bf(v.x); r.y = f2bf(v.y); r.z = f2bf(v.z); r.w = f2bf(v.w);
  o[i] = r;
}

// ------------- transpose + convert weights: Wt[n][k] = W[k][n] -------------
__global__ void k_transpose(const float* __restrict__ w0, const float* __restrict__ w1,
                            unsigned short* __restrict__ t0, unsigned short* __restrict__ t1) {
  __shared__ float tile[32][33];
  const float* src = blockIdx.z ? w1 : w0;
  unsigned short* dst = blockIdx.z ? t1 : t0;
  int bx = blockIdx.x * 32;  // n (col of W)
  int by = blockIdx.y * 32;  // k (row of W)
  int tx = threadIdx.x & 31, ty = threadIdx.x >> 5;  // 256 threads
#pragma unroll
  for (int r = 0; r < 32; r += 8)
    tile[ty + r][tx] = src[(by + ty + r) * DM + bx + tx];
  __syncthreads();
#pragma unroll
  for (int r = 0; r < 32; r += 8)
    dst[(bx + ty + r) * DM + by + tx] = f2bf(tile[tx][ty + r]);
}

// ---------------- bf16 MFMA GEMM: C = A @ Wt^T + bias ----------------
// 256x256 tile, BK=32, 8 waves (2M x 4N), per-wave 128x64 output.
// 4-deep LDS ring (128 KiB), counted vmcnt(8), both-sides XOR swizzle,
// 2 phases/tile, setprio around MFMA clusters.
// MODE 0: bf16 out (proj). MODE 1: fp32 out, rows < Mvalid.
template <int MODE>
__global__ __launch_bounds__(512, 2) void k_gemm(const unsigned short* __restrict__ A16,
                                                 const unsigned short* __restrict__ Bt16,
                                                 const float* __restrict__ bias,
                                                 unsigned short* __restrict__ outb,
                                                 float* __restrict__ outf, int Mvalid) {
  // ring: buf b at b*16384 elements; A at +0 (256x32), B at +8192 (256x32)
  __shared__ unsigned short lds[4 * 16384];  // 128 KiB

  const int tid = threadIdx.x;
  const int w = tid >> 6, l = tid & 63;
  const int wm = w >> 2, wn = w & 3;         // 2 x 4 wave grid
  const int rr = l & 15, kg = l >> 4;

  // bijective XCD swizzle (m204 general form; works for nwg%8 != 0)
  const int nwg = gridDim.x, orig = blockIdx.x;
  const int q = nwg >> 3, r8 = nwg & 7;
  const int xcd = orig & 7, idx = orig >> 3;
  const int wg = (xcd < r8 ? xcd * (q + 1) : r8 * (q + 1) + (xcd - r8) * q) + idx;
  const int bm = wg >> 2, bn = wg & 3;       // N=1024 -> 4 column tiles
  const int blockM = bm * 256;
  const int blockN = bn * 256;

  f32x4 acc[8][4];
#pragma unroll
  for (int m = 0; m < 8; m++)
#pragma unroll
    for (int n = 0; n < 4; n++) acc[m][n] = (f32x4){0.f, 0.f, 0.f, 0.f};

  // ---- staging geometry: wave w stages rows [w*32, w*32+32) of A and B tiles,
  // as 2 chunks of 16 rows; lane l -> row +(l>>2), physical slot l&3.
  // Global source is inverse-swizzled so that swizzled ds_read sees logical data.
  const unsigned short* pA[2];
  const unsigned short* pB[2];
#pragma unroll
  for (int cc = 0; cc < 2; cc++) {
    int rp = w * 32 + cc * 16 + (l >> 2);
    int sl = (l & 3) ^ ((rp >> 1) & 3);
    pA[cc] = A16 + (size_t)(blockM + rp) * DM + sl * 8;
    pB[cc] = Bt16 + (size_t)(blockN + rp) * DM + sl * 8;
  }

  // ---- fragment read offsets (elements), swizzled; constant across tiles
  int offA[8], offB[4];
#pragma unroll
  for (int mf = 0; mf < 8; mf++) {
    int rrow = wm * 128 + mf * 16 + rr;
    offA[mf] = rrow * 32 + ((kg ^ ((rrow >> 1) & 3)) * 8);
  }
#pragma unroll
  for (int nf = 0; nf < 4; nf++) {
    int rb = wn * 64 + nf * 16 + rr;
    offB[nf] = 8192 + rb * 32 + ((kg ^ ((rb >> 1) & 3)) * 8);
  }

  auto stageA = [&](int t) {
    unsigned short* d = lds + (t & 3) * 16384 + w * 1024;
#pragma unroll
    for (int cc = 0; cc < 2; cc++) gl_lds16(pA[cc] + (size_t)t * 32, d + cc * 512);
  };
  auto stageB = [&](int t) {
    unsigned short* d = lds + (t & 3) * 16384 + 8192 + w * 1024;
#pragma unroll
    for (int cc = 0; cc < 2; cc++) gl_lds16(pB[cc] + (size_t)t * 32, d + cc * 512);
  };

  // prologue: stage tiles 0,1,2 (12 gl_lds per thread in flight)
  stageA(0); stageB(0);
  stageA(1); stageB(1);
  stageA(2); stageB(2);

  for (int t = 0; t < NT; ++t) {
    // counted wait: confirm tile t landed; keep up to 2 tiles (8 loads) in flight
    if (t < NT - 2)       asm volatile("s_waitcnt vmcnt(8)" ::: "memory");
    else if (t == NT - 2) asm volatile("s_waitcnt vmcnt(4)" ::: "memory");
    else                  asm volatile("s_waitcnt vmcnt(0)" ::: "memory");
    __builtin_amdgcn_s_barrier();
    asm volatile("" ::: "memory");

    const unsigned short* buf = lds + (t & 3) * 16384;
    const bool do_stage = (t + 3 < NT);

    // ---- phase 0: m-frags 0..3 x all 4 n-frags (16 MFMA)
    bf16x8 bq[4], aq[4];
#pragma unroll
    for (int nf = 0; nf < 4; nf++) bq[nf] = *(const bf16x8*)(buf + offB[nf]);
#pragma unroll
    for (int mf = 0; mf < 4; mf++) aq[mf] = *(const bf16x8*)(buf + offA[mf]);
    if (do_stage) stageA(t + 3);
    __builtin_amdgcn_s_setprio(1);
#pragma unroll
    for (int mf = 0; mf < 4; mf++)
#pragma unroll
      for (int nf = 0; nf < 4; nf++)
        acc[mf][nf] = __builtin_amdgcn_mfma_f32_16x16x32_bf16(aq[mf], bq[nf], acc[mf][nf], 0, 0, 0);
    __builtin_amdgcn_s_setprio(0);
    __builtin_amdgcn_s_barrier();

    // ---- phase 1: m-frags 4..7 (B frags stay resident)
#pragma unroll
    for (int mf = 0; mf < 4; mf++) aq[mf] = *(const bf16x8*)(buf + offA[4 + mf]);
    if (do_stage) stageB(t + 3);
    __builtin_amdgcn_s_setprio(1);
#pragma unroll
    for (int mf = 0; mf < 4; mf++)
#pragma unroll
      for (int nf = 0; nf < 4; nf++)
        acc[4 + mf][nf] = __builtin_amdgcn_mfma_f32_16x16x32_bf16(aq[mf], bq[nf], acc[4 + mf][nf], 0, 0, 0);
    __builtin_amdgcn_s_setprio(0);
  }

  // epilogue: C/D mapping col=lane&15, row=(lane>>4)*4+j  [m89-verified]
#pragma unroll
  for (int nf = 0; nf < 4; nf++) {
    int col = blockN + wn * 64 + nf * 16 + (l & 15);
    float bv = bias[col];
#pragma unroll
    for (int mf = 0; mf < 8; mf++) {
      int row = blockM + wm * 128 + mf * 16 + (l >> 4) * 4;
#pragma unroll
      for (int j = 0; j < 4; j++) {
        float v = acc[mf][nf][j] + bv;
        if (MODE == 0) {
          outb[(size_t)(row + j) * DM + col] = f2bf(v);
        } else {
          if (row + j < Mvalid) outf[(size_t)(row + j) * DM + col] = v;
        }
      }
    }
  }
}

// ---------------- scan phase A: per-chunk local (zero-init) end state ----------------
__global__ void k_scan_partial(const unsigned short* __restrict__ proj,
                               const float* __restrict__ logit,
                               const float* __restrict__ z0,
                               float* __restrict__ chunkend) {
  int b = blockIdx.x >> 6, c = blockIdx.x & 63;
  int ch = threadIdx.x;  // 1024 channels = h*64+d
  float a = 1.f / (1.f + expf(-logit[ch >> 6]));
  int t0 = c * CL;
  const unsigned short* p = proj + (size_t)(b * T + t0) * DM + ch;
  float pprev = (t0 == 0) ? z0[ch] : bf2f(p[-DM]);
  float s = 0.f;
  for (int j = 0; j < CL; j++) {
    float pv = bf2f(p[(size_t)j * DM]);
    s = a * s + (1.f - a) * (pv - pprev);
    pprev = pv;
  }
  chunkend[(b * NCH + c) * DM + ch] = s;
}

// ---------------- scan phase B: serial cross-chunk combine ----------------
__global__ void k_scan_combine(const float* __restrict__ chunkend,
                               const float* __restrict__ logit,
                               const float* __restrict__ v0,
                               float* __restrict__ enter) {
  int b = blockIdx.x;
  int ch = threadIdx.x;
  float a = 1.f / (1.f + expf(-logit[ch >> 6]));
  float a2 = a * a, a4 = a2 * a2, a8 = a4 * a4, a16 = a8 * a8, a32 = a16 * a16;
  float aL = a32 * a32;  // a^64
  float e = v0[ch];      // s_{-1}
  enter[(b * NCH + 0) * DM + ch] = e;
  for (int c = 1; c < NCH; c++) {
    e = aL * e + chunkend[(b * NCH + c - 1) * DM + ch];
    enter[(b * NCH + c) * DM + ch] = e;
  }
}

// ---------------- scan phase C: final scan with entry states, write S (bf16) ----------------
__global__ void k_scan_final(const unsigned short* __restrict__ proj,
                             const float* __restrict__ logit,
                             const float* __restrict__ z0,
                             const float* __restrict__ v0,
                             const float* __restrict__ enter,
                             unsigned short* __restrict__ S) {
  int b = blockIdx.x >> 6, c = blockIdx.x & 63;
  int ch = threadIdx.x;
  float a = 1.f / (1.f + expf(-logit[ch >> 6]));
  int t0 = c * CL;
  const unsigned short* p = proj + (size_t)(b * T + t0) * DM + ch;
  unsigned short* so = S + (size_t)(b * (T + 1) + t0 + 1) * DM + ch;
  float pprev = (t0 == 0) ? z0[ch] : bf2f(p[-DM]);
  float s = enter[(b * NCH + c) * DM + ch];
  if (c == 0) S[(size_t)b * (T + 1) * DM + ch] = f2bf(v0[ch]);  // row 0 = v0
  for (int j = 0; j < CL; j++) {
    float pv = bf2f(p[(size_t)j * DM]);
    s = a * s + (1.f - a) * (pv - pprev);
    pprev = pv;
    so[(size_t)j * DM] = f2bf(s);
  }
}

// zero the padded S rows [M2, M2P) so GEMM2 staging reads are benign
__global__ void k_pad(unsigned short* __restrict__ S) {
  int i = blockIdx.x * 256 + threadIdx.x;  // 248*1024 = 253952 elements
  if (i < (M2P - M2) * DM) S[(size_t)M2 * DM + i] = 0;
}

extern "C" void kernel_launch(void* const* d_in, const int* in_sizes, int n_in,
                              void* d_out, int out_size, void* d_ws, size_t ws_size,
                              hipStream_t stream) {
  const float* inputs = (const float*)d_in[0];
  const float* z0     = (const float*)d_in[1];
  const float* W_in   = (const float*)d_in[2];
  const float* b_in   = (const float*)d_in[3];
  const float* W_out  = (const float*)d_in[4];
  const float* b_out  = (const float*)d_in[5];
  const float* slogit = (const float*)d_in[6];
  const float* v0     = (const float*)d_in[7];
  float* out = (float*)d_out;

  char* ws = (char*)d_ws;
  unsigned short* X16   = (unsigned short*)(ws);                    // 67,108,864 B
  unsigned short* P16   = (unsigned short*)(ws + 67108864);         // 67,108,864 B
  unsigned short* S16   = (unsigned short*)(ws + 134217728);        // 67,633,152 B (33024 rows)
  unsigned short* WTin  = (unsigned short*)(ws + 201850880);        // 2,097,152 B
  unsigned short* WTout = (unsigned short*)(ws + 203948032);        // 2,097,152 B
  float* chunkend       = (float*)(ws + 206045184);                 // 2,097,152 B
  float* enter          = (float*)(ws + 208142336);                 // 2,097,152 B

  // 1. convert inputs to bf16
  k_cvt_x<<<32768, 256, 0, stream>>>((const float4*)inputs, (ushort4*)X16);
  // 2. transpose+convert both weights
  k_transpose<<<dim3(32, 32, 2), 256, 0, stream>>>(W_in, W_out, WTin, WTout);
  // 3. GEMM1: proj = inputs @ W_in + b_in   (bf16 out), 128x4 = 512 wgs
  k_gemm<0><<<dim3((M1 / 256) * 4), 512, 0, stream>>>(X16, WTin, b_in, P16, nullptr, M1);
  // 4. scan: temporal diff + exponential smoothing
  k_scan_partial<<<dim3(BATCH * NCH), 1024, 0, stream>>>(P16, slogit, z0, chunkend);
  k_scan_combine<<<dim3(BATCH), 1024, 0, stream>>>(chunkend, slogit, v0, enter);
  k_scan_final<<<dim3(BATCH * NCH), 1024, 0, stream>>>(P16, slogit, z0, v0, enter, S16);
  k_pad<<<dim3(992), 256, 0, stream>>>(S16);
  // 5. GEMM2: out = S @ W_out + b_out  (fp32 out, 32776 valid rows of 33024), 129x4 = 516 wgs
  k_gemm<1><<<dim3((M2P / 256) * 4), 512, 0, stream>>>(S16, WTout, b_out, nullptr, out, M2);
}